// Round 10
// baseline (288.600 us; speedup 1.0000x reference)
//
#include <hip/hip_runtime.h>

#define S_LEN 2048
#define H_DIM 2048
#define NH 32
#define NKV 8
#define HD 64
#define RLEN 1024
#define KVTOT 3072
#define SCALE 0.125f
// SCALE * log2(e): fold into Q during RoPE so QK^T lands in log2 domain
#define QS 0.18033688011112042f
// 8 * log2(e): fixed softmax max in log2 domain
#define FIX8 11.541560327111707f

typedef unsigned short ushort_t;
using short8 = __attribute__((ext_vector_type(8))) short;
using f32x4 = __attribute__((ext_vector_type(4))) float;

__device__ __forceinline__ float b2f(unsigned short u) {
    union { unsigned int i; float f; } v;
    v.i = ((unsigned int)u) << 16;
    return v.f;
}
__device__ __forceinline__ unsigned short f2b(float f) {
    union { float f; unsigned int i; } v;
    v.f = f;
    unsigned int x = v.i;
    return (unsigned short)((x + 0x7fffu + ((x >> 16) & 1u)) >> 16);
}

// load 8 consecutive elements as bf16x8 from dual-dtype tensor
__device__ __forceinline__ uint4 ld8(const void* A, size_t idx, int F) {
    if (F) {
        const float* p = (const float*)A + idx;
        float4 f0 = ((const float4*)p)[0], f1 = ((const float4*)p)[1];
        ushort_t o[8];
        o[0] = f2b(f0.x); o[1] = f2b(f0.y); o[2] = f2b(f0.z); o[3] = f2b(f0.w);
        o[4] = f2b(f1.x); o[5] = f2b(f1.y); o[6] = f2b(f1.z); o[7] = f2b(f1.w);
        return *(uint4*)o;
    }
    return *(const uint4*)((const ushort_t*)A + idx);
}

// ---- dtype detector: flags[b] = 1 if tensor b is f32, 0 if bf16 ----
__global__ void detect9(const void* p0, const void* p1, const void* p2,
                        const void* p3, const void* p4, const void* p5,
                        const void* p6, const void* p7, const void* p8,
                        int* flags)
{
    __shared__ int bad;
    if (threadIdx.x == 0) bad = 0;
    __syncthreads();
    const void* ps[9] = {p0, p1, p2, p3, p4, p5, p6, p7, p8};
    const unsigned int* w = (const unsigned int*)ps[blockIdx.x];
    int cnt = 0;
    for (int i = threadIdx.x; i < 4096; i += blockDim.x) {
        unsigned int lo = w[i] & 0xFFFFu;
        unsigned int e = (lo >> 7) & 0xFFu;
        if (lo != 0u && (e < 90u || e > 140u)) ++cnt;
    }
    atomicAdd(&bad, cnt);
    __syncthreads();
    if (threadIdx.x == 0) flags[blockIdx.x] = (bad > 16) ? 1 : 0;
}

// ---- cvtW: transpose all 4 weights into WqkvT / WoT via blockIdx.z ----
__global__ __launch_bounds__(256) void cvtW(
    const void* __restrict__ Wq, const void* __restrict__ Wk,
    const void* __restrict__ Wv, const void* __restrict__ Wo,
    ushort_t* __restrict__ WqkvT, ushort_t* __restrict__ WoT,
    const int* __restrict__ flags)
{
    const int z = blockIdx.z;
    if ((z == 1 || z == 2) && blockIdx.x >= 8) return;
    const void* src = (z == 0) ? Wq : (z == 1) ? Wk : (z == 2) ? Wv : Wo;
    const int F = flags[5 + z];
    const int C = (z == 1 || z == 2) ? 512 : 2048;
    ushort_t* dst = (z == 3) ? WoT : WqkvT;
    const int rofs = (z == 1) ? 2048 : (z == 2) ? 2560 : 0;

    __shared__ ushort_t S[64 * 72];
    const int r0 = blockIdx.y * 64, c0 = blockIdx.x * 64;
    const int lr = threadIdx.x >> 2, lc = (threadIdx.x & 3) * 16;
    size_t base = (size_t)(r0 + lr) * C + c0 + lc;
    *(uint4*)&S[lr * 72 + lc] = ld8(src, base, F);
    *(uint4*)&S[lr * 72 + lc + 8] = ld8(src, base + 8, F);
    __syncthreads();
    const int wc = threadIdx.x >> 2, wr = (threadIdx.x & 3) * 16;
    ushort_t o[16];
#pragma unroll
    for (int j = 0; j < 16; ++j) o[j] = S[(wr + j) * 72 + wc];
    ushort_t* q = dst + (size_t)(rofs + c0 + wc) * 2048 + r0 + wr;
    *(uint4*)q = *(const uint4*)o;
    *(uint4*)(q + 8) = *(const uint4*)(o + 8);
}

// ---- dbuf MFMA GEMM, 64x128 tile: C(bf16) = A(dual) @ Bt(bf16)^T ----
__global__ __launch_bounds__(256) void gemm_qkv(
    const void* __restrict__ A, const ushort_t* __restrict__ Bt,
    ushort_t* __restrict__ C, int N, int K, const int* __restrict__ aF_)
{
    const int aF = *aF_;
    __shared__ __align__(16) ushort_t As[2][64 * 40];
    __shared__ __align__(16) ushort_t Bs[2][128 * 40];
    const int tid = threadIdx.x;
    const int wave = tid >> 6, lane = tid & 63;
    const int lq = lane & 15, quad = lane >> 4;
    const int m0 = blockIdx.y * 64, n0 = blockIdx.x * 128;
    const int wm = (wave & 1) * 32, wn = (wave >> 1) * 64;
    const int ar = tid >> 2, ak = (tid & 3) * 8;
    const int br = tid >> 1, bk = (tid & 1) * 16;
    const int nk = K >> 5;

    f32x4 acc[2][4];
#pragma unroll
    for (int i = 0; i < 2; ++i)
#pragma unroll
        for (int j = 0; j < 4; ++j) acc[i][j] = (f32x4){0.f, 0.f, 0.f, 0.f};

    const size_t aidx = (size_t)(m0 + ar) * K + ak;
    const ushort_t* bp = Bt + (size_t)(n0 + br) * K + bk;
    {
        uint4 a0 = ld8(A, aidx, aF);
        uint4 b0 = ((const uint4*)bp)[0], b1 = ((const uint4*)bp)[1];
        *(uint4*)&As[0][ar * 40 + ak] = a0;
        *(uint4*)&Bs[0][br * 40 + bk] = b0; *(uint4*)&Bs[0][br * 40 + bk + 8] = b1;
    }

    for (int kt = 0; kt < nk; ++kt) {
        const int cur = kt & 1;
        uint4 na0, nb0, nb1;
        const bool more = (kt + 1 < nk);
        if (more) {
            na0 = ld8(A, aidx + (kt + 1) * 32, aF);
            const ushort_t* bp2 = bp + (kt + 1) * 32;
            nb0 = ((const uint4*)bp2)[0]; nb1 = ((const uint4*)bp2)[1];
        }
        __syncthreads();
        short8 afr[2], bfr[4];
#pragma unroll
        for (int i = 0; i < 2; ++i)
            afr[i] = *(const short8*)&As[cur][(wm + i * 16 + lq) * 40 + quad * 8];
#pragma unroll
        for (int j = 0; j < 4; ++j)
            bfr[j] = *(const short8*)&Bs[cur][(wn + j * 16 + lq) * 40 + quad * 8];
#pragma unroll
        for (int i = 0; i < 2; ++i)
#pragma unroll
            for (int j = 0; j < 4; ++j)
                acc[i][j] = __builtin_amdgcn_mfma_f32_16x16x32_bf16(afr[i], bfr[j], acc[i][j], 0, 0, 0);
        __syncthreads();
        if (more) {
            const int nxt = cur ^ 1;
            *(uint4*)&As[nxt][ar * 40 + ak] = na0;
            *(uint4*)&Bs[nxt][br * 40 + bk] = nb0; *(uint4*)&Bs[nxt][br * 40 + bk + 8] = nb1;
        }
    }

#pragma unroll
    for (int i = 0; i < 2; ++i)
#pragma unroll
        for (int r = 0; r < 4; ++r) {
            ushort_t* cp = C + (size_t)(m0 + wm + i * 16 + quad * 4 + r) * N + n0 + wn + lq;
#pragma unroll
            for (int j = 0; j < 4; ++j) cp[j * 16] = f2b(acc[i][j][r]);
        }
}

// ---- dbuf MFMA GEMM, 64x128 tile, dual-dtype output ----
__global__ __launch_bounds__(256) void gemm_fin(
    const ushort_t* __restrict__ A, const ushort_t* __restrict__ Bt,
    void* __restrict__ Cv, int N, int K, const int* __restrict__ oF_)
{
    const int oF = *oF_;
    __shared__ __align__(16) ushort_t As[2][64 * 40];
    __shared__ __align__(16) ushort_t Bs[2][128 * 40];
    const int tid = threadIdx.x;
    const int wave = tid >> 6, lane = tid & 63;
    const int lq = lane & 15, quad = lane >> 4;
    const int m0 = blockIdx.y * 64, n0 = blockIdx.x * 128;
    const int wm = (wave & 1) * 32, wn = (wave >> 1) * 64;
    const int ar = tid >> 2, ak = (tid & 3) * 8;
    const int br = tid >> 1, bk = (tid & 1) * 16;
    const int nk = K >> 5;

    f32x4 acc[2][4];
#pragma unroll
    for (int i = 0; i < 2; ++i)
#pragma unroll
        for (int j = 0; j < 4; ++j) acc[i][j] = (f32x4){0.f, 0.f, 0.f, 0.f};

    const ushort_t* ap = A + (size_t)(m0 + ar) * K + ak;
    const ushort_t* bp = Bt + (size_t)(n0 + br) * K + bk;
    {
        uint4 a0 = ((const uint4*)ap)[0];
        uint4 b0 = ((const uint4*)bp)[0], b1 = ((const uint4*)bp)[1];
        *(uint4*)&As[0][ar * 40 + ak] = a0;
        *(uint4*)&Bs[0][br * 40 + bk] = b0; *(uint4*)&Bs[0][br * 40 + bk + 8] = b1;
    }

    for (int kt = 0; kt < nk; ++kt) {
        const int cur = kt & 1;
        uint4 na0, nb0, nb1;
        const bool more = (kt + 1 < nk);
        if (more) {
            na0 = *(const uint4*)(ap + (kt + 1) * 32);
            const ushort_t* bp2 = bp + (kt + 1) * 32;
            nb0 = ((const uint4*)bp2)[0]; nb1 = ((const uint4*)bp2)[1];
        }
        __syncthreads();
        short8 afr[2], bfr[4];
#pragma unroll
        for (int i = 0; i < 2; ++i)
            afr[i] = *(const short8*)&As[cur][(wm + i * 16 + lq) * 40 + quad * 8];
#pragma unroll
        for (int j = 0; j < 4; ++j)
            bfr[j] = *(const short8*)&Bs[cur][(wn + j * 16 + lq) * 40 + quad * 8];
#pragma unroll
        for (int i = 0; i < 2; ++i)
#pragma unroll
            for (int j = 0; j < 4; ++j)
                acc[i][j] = __builtin_amdgcn_mfma_f32_16x16x32_bf16(afr[i], bfr[j], acc[i][j], 0, 0, 0);
        __syncthreads();
        if (more) {
            const int nxt = cur ^ 1;
            *(uint4*)&As[nxt][ar * 40 + ak] = na0;
            *(uint4*)&Bs[nxt][br * 40 + bk] = nb0; *(uint4*)&Bs[nxt][br * 40 + bk + 8] = nb1;
        }
    }

#pragma unroll
    for (int i = 0; i < 2; ++i)
#pragma unroll
        for (int r = 0; r < 4; ++r) {
            size_t off = (size_t)(m0 + wm + i * 16 + quad * 4 + r) * N + n0 + wn + lq;
            if (oF) {
                float* cp = (float*)Cv + off;
#pragma unroll
                for (int j = 0; j < 4; ++j) cp[j * 16] = acc[i][j][r];
            } else {
                ushort_t* cp = (ushort_t*)Cv + off;
#pragma unroll
                for (int j = 0; j < 4; ++j) cp[j * 16] = f2b(acc[i][j][r]);
            }
        }
}

// ---- prepKV: z=0 -> V transpose into tiled vtall; z=1 -> K concat + fused RoPE ----
// vtall layout: [kvh][blk(96)][d(64)][32 kv]; ktall: [kvh][kv(3072)][d(64)].
__global__ __launch_bounds__(256) void prepKV(
    const void* __restrict__ rk, const void* __restrict__ rv,
    const ushort_t* __restrict__ qkvp,
    const void* __restrict__ cosv, const void* __restrict__ sinv,
    ushort_t* __restrict__ ktall, ushort_t* __restrict__ vtall,
    const int* __restrict__ flags)
{
    if (blockIdx.z == 0) {
        const int vF = flags[4];
        const int t = blockIdx.x;      // 0..47, <16 retrieval
        const int kvh = blockIdx.y;
        __shared__ ushort_t S[64 * 72];
        const int lr = threadIdx.x >> 2, lc = (threadIdx.x & 3) * 16;
        if (t < 16) {
            size_t base = ((size_t)kvh * RLEN + t * 64 + lr) * HD + lc;
            *(uint4*)&S[lr * 72 + lc] = ld8(rv, base, vF);
            *(uint4*)&S[lr * 72 + lc + 8] = ld8(rv, base + 8, vF);
        } else {
            const ushort_t* p = qkvp + (size_t)((t - 16) * 64 + lr) * 3072 + 2560 + kvh * HD + lc;
            *(uint4*)&S[lr * 72 + lc] = ((const uint4*)p)[0];
            *(uint4*)&S[lr * 72 + lc + 8] = ((const uint4*)p)[1];
        }
        __syncthreads();
        const int wc = threadIdx.x >> 2, wr = (threadIdx.x & 3) * 16;
        ushort_t o[16];
#pragma unroll
        for (int j = 0; j < 16; ++j) o[j] = S[(wr + j) * 72 + wc];
        const int blk = t * 2 + (wr >> 5);
        ushort_t* q = vtall + (((size_t)(kvh * 96 + blk) * 64 + wc) * 32) + (wr & 31);
        *(uint4*)q = *(const uint4*)o;
        *(uint4*)(q + 8) = *(const uint4*)(o + 8);
    } else {
        const int kF = flags[3], cF = flags[1], sF = flags[2];
        int flat = (blockIdx.y * 48 + blockIdx.x) * 256 + threadIdx.x;
        const int d0 = (flat & 3) * 8;
        const int p = (flat >> 2) % KVTOT;
        const int kvh = (flat >> 2) / KVTOT;
        ushort_t o0[8], o1[8];
        if (p < RLEN) {
            size_t base = ((size_t)kvh * RLEN + p) * HD;
            *(uint4*)o0 = ld8(rk, base + d0, kF);
            *(uint4*)o1 = ld8(rk, base + d0 + 32, kF);
        } else {
            const int si = p - RLEN;
            const ushort_t* s = qkvp + (size_t)si * 3072 + 2048 + kvh * HD;
            uint4 u0 = *(const uint4*)(s + d0);
            uint4 u1 = *(const uint4*)(s + d0 + 32);
            const ushort_t* a16 = (const ushort_t*)&u0;
            const ushort_t* b16 = (const ushort_t*)&u1;
            int ci = si * HD + d0;
            float c0[8], c1[8], s0[8], s1[8];
            if (cF) {
                const float* cp = (const float*)cosv + ci;
#pragma unroll
                for (int j = 0; j < 8; ++j) { c0[j] = cp[j]; c1[j] = cp[j + 32]; }
            } else {
                const ushort_t* cp = (const ushort_t*)cosv + ci;
#pragma unroll
                for (int j = 0; j < 8; ++j) { c0[j] = b2f(cp[j]); c1[j] = b2f(cp[j + 32]); }
            }
            if (sF) {
                const float* sp = (const float*)sinv + ci;
#pragma unroll
                for (int j = 0; j < 8; ++j) { s0[j] = sp[j]; s1[j] = sp[j + 32]; }
            } else {
                const ushort_t* sp = (const ushort_t*)sinv + ci;
#pragma unroll
                for (int j = 0; j < 8; ++j) { s0[j] = b2f(sp[j]); s1[j] = b2f(sp[j + 32]); }
            }
#pragma unroll
            for (int j = 0; j < 8; ++j) {
                float a = b2f(a16[j]), b = b2f(b16[j]);
                o0[j] = f2b(a * c0[j] - b * s0[j]);
                o1[j] = f2b(b * c1[j] + a * s1[j]);
            }
        }
        ushort_t* q = ktall + ((size_t)kvh * KVTOT + p) * HD;
        *(uint4*)(q + d0) = *(const uint4*)o0;
        *(uint4*)(q + d0 + 32) = *(const uint4*)o1;
    }
}

// ---- Flash attention v6: cross-chunk K-prefetch pipeline ----
// K loads for chunk c+1 issue right after the barrier releasing chunk c's
// compute; the waitcnt lands at the next iteration's LDS write, hidden under
// ~500 cyc of QK/softmax/PV. V kc0/kc1 prefetched per chunk as before.
__global__ __launch_bounds__(256) void fattn(
    const ushort_t* __restrict__ qkvp, const ushort_t* __restrict__ ktall,
    const ushort_t* __restrict__ vtall, ushort_t* __restrict__ attno,
    const void* __restrict__ cosv, const void* __restrict__ sinv,
    const int* __restrict__ flags)
{
    const int cF = flags[1], sF = flags[2];
    const int h = blockIdx.x;
    const int qb = 31 - blockIdx.y;     // heavy blocks first
    const int kvh = h >> 2;
    const int tid = threadIdx.x;
    const int wave = tid >> 6;
    const int lane = tid & 63;
    const int lq = lane & 15;
    const int quad = lane >> 4;
    const int rb64 = ((qb < 17 ? qb : 16) - 1) * 64;

    __shared__ __align__(16) ushort_t Ks[128 * 72];
    __shared__ __align__(16) ushort_t Ps[4 * 16 * 136];
    ushort_t* pw = &Ps[wave * 16 * 136];

    // ---- Q load + fused RoPE, SCALE*log2e folded ----
    short8 qfrag[2];
    {
        const int row_g = qb * 64 + wave * 16 + lq;
        const ushort_t* qrow = qkvp + (size_t)row_g * 3072 + h * HD;
        short8 t0 = *(const short8*)(qrow + quad * 8);
        short8 t1 = *(const short8*)(qrow + 32 + quad * 8);
        const int ci = row_g * HD + quad * 8;
        float c0[8], c1[8], s0[8], s1[8];
        if (cF) {
            const float* cp = (const float*)cosv + ci;
#pragma unroll
            for (int j = 0; j < 8; ++j) { c0[j] = cp[j]; c1[j] = cp[j + 32]; }
        } else {
            const ushort_t* cp = (const ushort_t*)cosv + ci;
#pragma unroll
            for (int j = 0; j < 8; ++j) { c0[j] = b2f(cp[j]); c1[j] = b2f(cp[j + 32]); }
        }
        if (sF) {
            const float* sp = (const float*)sinv + ci;
#pragma unroll
            for (int j = 0; j < 8; ++j) { s0[j] = sp[j]; s1[j] = sp[j + 32]; }
        } else {
            const ushort_t* sp = (const ushort_t*)sinv + ci;
#pragma unroll
            for (int j = 0; j < 8; ++j) { s0[j] = b2f(sp[j]); s1[j] = b2f(sp[j + 32]); }
        }
#pragma unroll
        for (int j = 0; j < 8; ++j) {
            float a = b2f((unsigned short)t0[j]), b = b2f((unsigned short)t1[j]);
            qfrag[0][j] = (short)f2b((a * c0[j] - b * s0[j]) * QS);
            qfrag[1][j] = (short)f2b((b * c1[j] + a * s1[j]) * QS);
        }
    }

    f32x4 oacc[4];
#pragma unroll
    for (int nt = 0; nt < 4; ++nt) oacc[nt] = (f32x4){0.f, 0.f, 0.f, 0.f};
    float lsum[4] = {0.f, 0.f, 0.f, 0.f};

    const int Lq = (qb > 0) ? qb * 64 + 128 : 64;
    const int nch = (Lq + 127) >> 7;
    const ushort_t* kbase = ktall + (size_t)kvh * KVTOT * HD;
    const ushort_t* vbase = vtall + (size_t)kvh * 96 * 2048;

    const int krow = tid >> 1;
    const int kd0 = (tid & 1) * 32;

    // ---- preload chunk 0 K into registers ----
    uint4 kreg0, kreg1, kreg2, kreg3;
    {
        uint4 z = {0, 0, 0, 0};
        kreg0 = z; kreg1 = z; kreg2 = z; kreg3 = z;
        int p = krow;
        if (p < Lq) {
            int pk = (qb > 0) ? ((p < 64) ? rb64 + p : 960 + p) : RLEN + p;
            const uint4* s = (const uint4*)(kbase + (size_t)pk * HD + kd0);
            kreg0 = s[0]; kreg1 = s[1]; kreg2 = s[2]; kreg3 = s[3];
        }
    }

    for (int c = 0; c < nch; ++c) {
        // ---- write prefetched K to LDS ----
        {
            uint4* dk = (uint4*)&Ks[krow * 72 + kd0];
            dk[0] = kreg0; dk[1] = kreg1; dk[2] = kreg2; dk[3] = kreg3;
        }
        __syncthreads();

        // ---- issue next chunk's K loads (awaited at next iteration's write) ----
        if (c + 1 < nch) {
            uint4 z = {0, 0, 0, 0};
            kreg0 = z; kreg1 = z; kreg2 = z; kreg3 = z;
            int p = (c + 1) * 128 + krow;
            if (p < Lq) {
                int pk = (qb > 0) ? ((p < 64) ? rb64 + p : 960 + p) : RLEN + p;
                const uint4* s = (const uint4*)(kbase + (size_t)pk * HD + kd0);
                kreg0 = s[0]; kreg1 = s[1]; kreg2 = s[2]; kreg3 = s[3];
            }
        }

        // ---- V prefetch kc0, kc1 (direct-global frags for chunk c) ----
        int vblk[4];
#pragma unroll
        for (int kc = 0; kc < 4; ++kc) {
            int p = c * 128 + kc * 32;
            int pk = (qb > 0) ? ((p < 64) ? rb64 + p : 960 + p) : RLEN + p;
            if (pk > KVTOT - 1) pk = KVTOT - 1;   // clamped keys have P==0 (masked)
            vblk[kc] = pk >> 5;
        }
        short8 vfA[4], vfB[4];
#pragma unroll
        for (int ntd = 0; ntd < 4; ++ntd)
            vfA[ntd] = *(const short8*)(vbase + ((size_t)vblk[0] * 64 + ntd * 16 + lq) * 32 + quad * 8);
#pragma unroll
        for (int ntd = 0; ntd < 4; ++ntd)
            vfB[ntd] = *(const short8*)(vbase + ((size_t)vblk[1] * 64 + ntd * 16 + lq) * 32 + quad * 8);

        // ---- S (log2 domain) + fixed-max exp2 + P to per-wave LDS ----
        const bool lastc = (c == nch - 1) || (qb == 0);
#pragma unroll
        for (int nt = 0; nt < 8; ++nt) {
            f32x4 a = (f32x4){0.f, 0.f, 0.f, 0.f};
            a = __builtin_amdgcn_mfma_f32_16x16x32_bf16(qfrag[0],
                *(const short8*)&Ks[(nt * 16 + lq) * 72 + quad * 8], a, 0, 0, 0);
            a = __builtin_amdgcn_mfma_f32_16x16x32_bf16(qfrag[1],
                *(const short8*)&Ks[(nt * 16 + lq) * 72 + 32 + quad * 8], a, 0, 0, 0);
            const int p = c * 128 + nt * 16 + lq;
#pragma unroll
            for (int r = 0; r < 4; ++r) {
                float pexp = exp2f(a[r] - FIX8);
                if (lastc) {
                    const int qg = qb * 64 + wave * 16 + quad * 4 + r;
                    bool valid;
                    if (qb > 0) valid = (p < 64) || ((p - 64) >= 1 && (p - 64) <= qg);
                    else        valid = (p >= 1 && p <= qg);
                    if (!valid) pexp = 0.f;
                } else if (c == 0) {
                    if (p == 64) pexp = 0.f;   // self position 0
                }
                lsum[r] += pexp;
                pw[(quad * 4 + r) * 136 + nt * 16 + lq] = f2b(pexp);
            }
        }

        // ---- O += P V : kc0/kc1 from prefetch; kc2/kc3 loaded mid-loop ----
#pragma unroll
        for (int kc = 0; kc < 4; ++kc) {
            short8 pa = *(const short8*)&pw[lq * 136 + kc * 32 + quad * 8];
            short8 vf0, vf1, vf2, vf3;
            if (kc == 0)      { vf0 = vfA[0]; vf1 = vfA[1]; vf2 = vfA[2]; vf3 = vfA[3]; }
            else if (kc == 1) { vf0 = vfB[0]; vf1 = vfB[1]; vf2 = vfB[2]; vf3 = vfB[3]; }
            else {
                const int b = vblk[kc];
                vf0 = *(const short8*)(vbase + ((size_t)b * 64 + 0 * 16 + lq) * 32 + quad * 8);
                vf1 = *(const short8*)(vbase + ((size_t)b * 64 + 1 * 16 + lq) * 32 + quad * 8);
                vf2 = *(const short8*)(vbase + ((size_t)b * 64 + 2 * 16 + lq) * 32 + quad * 8);
                vf3 = *(const short8*)(vbase + ((size_t)b * 64 + 3 * 16 + lq) * 32 + quad * 8);
            }
            oacc[0] = __builtin_amdgcn_mfma_f32_16x16x32_bf16(pa, vf0, oacc[0], 0, 0, 0);
            oacc[1] = __builtin_amdgcn_mfma_f32_16x16x32_bf16(pa, vf1, oacc[1], 0, 0, 0);
            oacc[2] = __builtin_amdgcn_mfma_f32_16x16x32_bf16(pa, vf2, oacc[2], 0, 0, 0);
            oacc[3] = __builtin_amdgcn_mfma_f32_16x16x32_bf16(pa, vf3, oacc[3], 0, 0, 0);
        }
        __syncthreads();
    }

    // ---- epilogue: reduce lsum over lq lanes, normalize, write ----
#pragma unroll
    for (int r = 0; r < 4; ++r) {
        float v = lsum[r];
        v += __shfl_xor(v, 1, 64); v += __shfl_xor(v, 2, 64);
        v += __shfl_xor(v, 4, 64); v += __shfl_xor(v, 8, 64);
        lsum[r] = v;
    }
#pragma unroll
    for (int r = 0; r < 4; ++r) {
        const int qg = qb * 64 + wave * 16 + quad * 4 + r;
        const float inv = (qg == 0) ? 0.f : 1.f / lsum[r];
        ushort_t* orow = attno + (size_t)qg * 2048 + h * HD;
#pragma unroll
        for (int nt = 0; nt < 4; ++nt)
            orow[nt * 16 + lq] = f2b(oacc[nt][r] * inv);
    }
}

extern "C" void kernel_launch(void* const* d_in, const int* in_sizes, int n_in,
                              void* d_out, int out_size, void* d_ws, size_t ws_size,
                              hipStream_t stream) {
    const void* hs   = d_in[0];
    const void* cosv = d_in[1];
    const void* sinv = d_in[2];
    const void* rk   = d_in[3];
    const void* rv   = d_in[4];
    const void* Wq   = d_in[5];
    const void* Wk   = d_in[6];
    const void* Wv   = d_in[7];
    const void* Wo   = d_in[8];

    char* ws = (char*)d_ws;
    int*      flags  = (int*)ws;                          // @0
    ushort_t* ktall  = (ushort_t*)(ws + (1u  << 20));     // 1..4.25 MB
    ushort_t* vtall  = (ushort_t*)(ws + (1u << 20) + (13u << 18));
    ushort_t* WqkvT  = (ushort_t*)(ws + (9u  << 20));     // 9..21 MB [3072][2048]
    ushort_t* attno  = WqkvT;                             // after WqkvT dead
    ushort_t* WoT    = (ushort_t*)(ws + (21u << 20));     // 21..29 MB
    ushort_t* qkvp   = (ushort_t*)(ws + (29u << 20));     // 29..41 MB [2048][3072]

    detect9<<<9, 256, 0, stream>>>(hs, cosv, sinv, rk, rv, Wq, Wk, Wv, Wo, flags);

    cvtW<<<dim3(32, 32, 4), 256, 0, stream>>>(Wq, Wk, Wv, Wo, WqkvT, WoT, flags);

    gemm_qkv<<<dim3(3072 / 128, 2048 / 64), 256, 0, stream>>>(hs, WqkvT, qkvp, 3072, 2048, flags + 0);

    prepKV<<<dim3(48, 8, 2), 256, 0, stream>>>(rk, rv, qkvp, cosv, sinv, ktall, vtall, flags);

    fattn<<<dim3(NH, 32), 256, 0, stream>>>(qkvp, ktall, vtall, attno, cosv, sinv, flags);

    gemm_fin<<<dim3(2048 / 128, 2048 / 64), 256, 0, stream>>>(attno, WoT, d_out, 2048, 2048, flags + 0);
}